// Round 4
// baseline (31.379 us; speedup 1.0000x reference)
//
#include <hip/hip_runtime.h>
#include <math.h>

#define EPS 1e-10f
#define FAR_DELTA 1e10f

// 32 lanes per ray, 4 samples per lane, 2 rays per wave, grid-stride with a
// 2-deep software pipeline (next ray's loads issued before current compute).
// D=128, C=3. All global loads are float4 (16B/lane).
__global__ void __launch_bounds__(256) volrend_d128(
    const float* __restrict__ density,   // (N,128)
    const float* __restrict__ feature,   // (N,128,3)
    const float* __restrict__ depth,     // (N,128)
    float* __restrict__ out_feat,        // (N,3)
    float* __restrict__ out_depth,       // (N,)
    int N)
{
    const int rlane = threadIdx.x & 31;                          // lane in ray group
    const int group = (blockIdx.x * blockDim.x + threadIdx.x) >> 5;
    const int gstride = (gridDim.x * blockDim.x) >> 5;           // total ray groups

    int ray = group;
    if (ray >= N) return;

    // ---- stage 0: load current ray ----
    float4 dp = *reinterpret_cast<const float4*>(depth   + (size_t)ray * 128 + 4 * rlane);
    float4 dn = *reinterpret_cast<const float4*>(density + (size_t)ray * 128 + 4 * rlane);
    const float4* fp0 = reinterpret_cast<const float4*>(feature + (size_t)ray * 384 + 12 * rlane);
    float4 fA = fp0[0];
    float4 fB = fp0[1];
    float4 fC = fp0[2];

    while (true) {
        const int nray = ray + gstride;
        const bool have_next = nray < N;

        // ---- prefetch next ray (independent of current compute chain) ----
        float4 ndp, ndn, nfA, nfB, nfC;
        if (have_next) {
            ndp = *reinterpret_cast<const float4*>(depth   + (size_t)nray * 128 + 4 * rlane);
            ndn = *reinterpret_cast<const float4*>(density + (size_t)nray * 128 + 4 * rlane);
            const float4* nfp = reinterpret_cast<const float4*>(feature + (size_t)nray * 384 + 12 * rlane);
            nfA = nfp[0];
            nfB = nfp[1];
            nfC = nfp[2];
        }

        // ---- compute current ray ----
        // deltas: consecutive diffs; delta3 needs next lane's dp.x; last sample
        // of the ray gets the 1e10 sentinel.
        const float dnext = __shfl_down(dp.x, 1, 32);
        const float delta0 = dp.y - dp.x;
        const float delta1 = dp.z - dp.y;
        const float delta2 = dp.w - dp.z;
        const float delta3 = (rlane == 31) ? FAR_DELTA : (dnext - dp.w);

        const float s0 = fmaf(-dn.x, delta0, EPS);
        const float s1 = fmaf(-dn.y, delta1, EPS);
        const float s2 = fmaf(-dn.z, delta2, EPS);
        const float s3 = fmaf(-dn.w, delta3, EPS);

        // Exclusive prefix sum over the ray's 128 samples.
        // CRITICAL: s3 at rlane 31 is ~-2e10 (sentinel); the reference's
        // exclusive cumsum never includes s[D-1], and f32-summing it would
        // absorb the ~-4 prefix (ulp(2e10) ~ 2048). Mask it out of the scan.
        const float s3_scan = (rlane == 31) ? 0.0f : s3;
        const float quad = s0 + s1 + s2 + s3_scan;
        float scan = quad;
        #pragma unroll
        for (int off = 1; off < 32; off <<= 1) {
            const float t = __shfl_up(scan, off, 32);
            if (rlane >= off) scan += t;
        }
        const float excl = scan - quad;        // sum of s over samples [0, 4r)
        const float logT0 = excl;
        const float logT1 = excl + s0;
        const float logT2 = logT1 + s1;
        const float logT3 = logT2 + s2;

        const float w0 = __expf(logT0) * (1.0f - __expf(s0));
        const float w1 = __expf(logT1) * (1.0f - __expf(s1));
        const float w2 = __expf(logT2) * (1.0f - __expf(s2));
        const float w3 = __expf(logT3) * (1.0f - __expf(s3));

        float fa0 = w0 * fA.x + w1 * fA.w + w2 * fB.z + w3 * fC.y;
        float fa1 = w0 * fA.y + w1 * fB.x + w2 * fB.w + w3 * fC.z;
        float fa2 = w0 * fA.z + w1 * fB.y + w2 * fC.x + w3 * fC.w;
        float da  = w0 * dp.x + w1 * dp.y + w2 * dp.z + w3 * dp.w;

        // Butterfly reduce within the 32-lane group.
        #pragma unroll
        for (int off = 16; off >= 1; off >>= 1) {
            fa0 += __shfl_xor(fa0, off);
            fa1 += __shfl_xor(fa1, off);
            fa2 += __shfl_xor(fa2, off);
            da  += __shfl_xor(da,  off);
        }

        if (rlane == 0) {
            out_feat[(size_t)ray * 3 + 0] = fa0;
            out_feat[(size_t)ray * 3 + 1] = fa1;
            out_feat[(size_t)ray * 3 + 2] = fa2;
            out_depth[ray] = da;
        }

        if (!have_next) break;
        ray = nray;
        dp = ndp; dn = ndn; fA = nfA; fB = nfB; fC = nfC;
    }
}

// Generic fallback: one thread per ray, sequential scan (any D, C<=8).
__global__ void volrend_generic(
    const float* __restrict__ density,
    const float* __restrict__ feature,
    const float* __restrict__ depth,
    float* __restrict__ out,  // feat (N,C) then depth (N,)
    int N, int D, int C)
{
    const int ray = blockIdx.x * blockDim.x + threadIdx.x;
    if (ray >= N) return;
    float logT = 0.0f;
    float facc[8];
    for (int c = 0; c < 8; ++c) facc[c] = 0.0f;
    float dacc = 0.0f;
    const size_t base = (size_t)ray * D;
    for (int d = 0; d < D; ++d) {
        const float dv = depth[base + d];
        const float delta = (d == D - 1) ? FAR_DELTA : (depth[base + d + 1] - dv);
        const float s = fmaf(-density[base + d], delta, EPS);
        const float w = expf(logT) * (1.0f - expf(s));
        for (int c = 0; c < C && c < 8; ++c)
            facc[c] += w * feature[(base + d) * C + c];
        dacc += w * dv;
        logT += s;
    }
    for (int c = 0; c < C && c < 8; ++c) out[(size_t)ray * C + c] = facc[c];
    out[(size_t)N * C + ray] = dacc;
}

extern "C" void kernel_launch(void* const* d_in, const int* in_sizes, int n_in,
                              void* d_out, int out_size, void* d_ws, size_t ws_size,
                              hipStream_t stream) {
    const float* density = (const float*)d_in[0];
    const float* feature = (const float*)d_in[1];
    const float* depth   = (const float*)d_in[2];
    float* out = (float*)d_out;

    const long ND  = in_sizes[0];
    const long NDC = in_sizes[1];
    const int C = (int)(NDC / ND);
    const int N = out_size / (C + 1);
    const int D = (int)(ND / N);

    if (D == 128 && C == 3) {
        // Persistent-ish: 2048 blocks (8/CU) x 8 ray-groups = 16384 groups;
        // each group walks N/16384 = 4 rays with a 2-deep pipeline.
        int groups_needed = (N + 0);               // one group per ray max
        int blocks = 2048;
        if (blocks * 8 > groups_needed) blocks = (groups_needed + 7) / 8;
        volrend_d128<<<blocks, 256, 0, stream>>>(density, feature, depth,
                                                 out, out + (size_t)N * 3, N);
    } else {
        const int threads = 256;
        volrend_generic<<<(N + threads - 1) / threads, threads, 0, stream>>>(
            density, feature, depth, out, N, D, C);
    }
}

// Round 5
// 29.224 us; speedup vs baseline: 1.0737x; 1.0737x over previous
//
#include <hip/hip_runtime.h>
#include <math.h>

#define EPS 1e-10f
#define FAR_DELTA 1e10f

// 32 lanes per ray, 4 samples per lane, 2 rays per wave. D=128, C=3.
// All global loads are float4 (16B/lane, coalescing sweet spot).
// NOTE: persistent/grid-stride + 2-deep prefetch variant was tried (R4) and
// REGRESSED (31.4 vs 29.5 us): VGPR 20->36 cut occupancy 68%->55%; TLP was
// already hiding latency. Keep the simple high-occupancy form.
__global__ void __launch_bounds__(256) volrend_d128(
    const float* __restrict__ density,   // (N,128)
    const float* __restrict__ feature,   // (N,128,3)
    const float* __restrict__ depth,     // (N,128)
    float* __restrict__ out_feat,        // (N,3)
    float* __restrict__ out_depth,       // (N,)
    int N)
{
    const int half = threadIdx.x >> 5;            // which 32-lane group in block (0..7)
    const int rlane = threadIdx.x & 31;           // lane within the ray group
    const int ray = blockIdx.x * 8 + half;
    if (ray >= N) return;

    // Lane owns samples 4r..4r+3; fully dense float4 loads.
    const float4 dp = *reinterpret_cast<const float4*>(depth   + (size_t)ray * 128 + 4 * rlane);
    const float4 dn = *reinterpret_cast<const float4*>(density + (size_t)ray * 128 + 4 * rlane);
    const float4* fp = reinterpret_cast<const float4*>(feature + (size_t)ray * 384 + 12 * rlane);
    const float4 fA = fp[0];  // feat[4r+0][0..2], feat[4r+1][0]
    const float4 fB = fp[1];  // feat[4r+1][1..2], feat[4r+2][0..1]
    const float4 fC = fp[2];  // feat[4r+2][2],    feat[4r+3][0..2]

    // deltas: consecutive diffs; delta3 needs next lane's dp.x (same 32-group);
    // last sample of the ray gets the 1e10 sentinel.
    const float dnext = __shfl_down(dp.x, 1, 32);
    const float delta0 = dp.y - dp.x;
    const float delta1 = dp.z - dp.y;
    const float delta2 = dp.w - dp.z;
    const float delta3 = (rlane == 31) ? FAR_DELTA : (dnext - dp.w);

    const float s0 = fmaf(-dn.x, delta0, EPS);
    const float s1 = fmaf(-dn.y, delta1, EPS);
    const float s2 = fmaf(-dn.z, delta2, EPS);
    const float s3 = fmaf(-dn.w, delta3, EPS);

    // Exclusive prefix sum of s over the 128 samples of this ray.
    // CRITICAL: s3 at rlane 31 is ~-2e10 (sentinel); the reference's exclusive
    // cumsum never includes s[D-1], and f32-summing it would absorb the ~-4
    // prefix (ulp(2e10) ~ 2048). Mask it out of the scan; still used for w3.
    const float s3_scan = (rlane == 31) ? 0.0f : s3;
    const float quad = s0 + s1 + s2 + s3_scan;
    float scan = quad;
    #pragma unroll
    for (int off = 1; off < 32; off <<= 1) {
        const float t = __shfl_up(scan, off, 32);
        if (rlane >= off) scan += t;
    }
    const float excl = scan - quad;        // sum of s over samples [0, 4r)
    const float logT0 = excl;
    const float logT1 = excl + s0;
    const float logT2 = logT1 + s1;
    const float logT3 = logT2 + s2;

    const float w0 = __expf(logT0) * (1.0f - __expf(s0));
    const float w1 = __expf(logT1) * (1.0f - __expf(s1));
    const float w2 = __expf(logT2) * (1.0f - __expf(s2));
    const float w3 = __expf(logT3) * (1.0f - __expf(s3));

    // Weighted accumulation: 3 feature channels + depth.
    float fa0 = w0 * fA.x + w1 * fA.w + w2 * fB.z + w3 * fC.y;
    float fa1 = w0 * fA.y + w1 * fB.x + w2 * fB.w + w3 * fC.z;
    float fa2 = w0 * fA.z + w1 * fB.y + w2 * fC.x + w3 * fC.w;
    float da  = w0 * dp.x + w1 * dp.y + w2 * dp.z + w3 * dp.w;

    // Butterfly reduce within the 32-lane group (xor offsets stay in-group).
    #pragma unroll
    for (int off = 16; off >= 1; off >>= 1) {
        fa0 += __shfl_xor(fa0, off);
        fa1 += __shfl_xor(fa1, off);
        fa2 += __shfl_xor(fa2, off);
        da  += __shfl_xor(da,  off);
    }

    if (rlane == 0) {
        out_feat[(size_t)ray * 3 + 0] = fa0;
        out_feat[(size_t)ray * 3 + 1] = fa1;
        out_feat[(size_t)ray * 3 + 2] = fa2;
        out_depth[ray] = da;
    }
}

// Generic fallback: one thread per ray, sequential scan (any D, C<=8).
__global__ void volrend_generic(
    const float* __restrict__ density,
    const float* __restrict__ feature,
    const float* __restrict__ depth,
    float* __restrict__ out,  // feat (N,C) then depth (N,)
    int N, int D, int C)
{
    const int ray = blockIdx.x * blockDim.x + threadIdx.x;
    if (ray >= N) return;
    float logT = 0.0f;
    float facc[8];
    for (int c = 0; c < 8; ++c) facc[c] = 0.0f;
    float dacc = 0.0f;
    const size_t base = (size_t)ray * D;
    for (int d = 0; d < D; ++d) {
        const float dv = depth[base + d];
        const float delta = (d == D - 1) ? FAR_DELTA : (depth[base + d + 1] - dv);
        const float s = fmaf(-density[base + d], delta, EPS);
        const float w = expf(logT) * (1.0f - expf(s));
        for (int c = 0; c < C && c < 8; ++c)
            facc[c] += w * feature[(base + d) * C + c];
        dacc += w * dv;
        logT += s;
    }
    for (int c = 0; c < C && c < 8; ++c) out[(size_t)ray * C + c] = facc[c];
    out[(size_t)N * C + ray] = dacc;
}

extern "C" void kernel_launch(void* const* d_in, const int* in_sizes, int n_in,
                              void* d_out, int out_size, void* d_ws, size_t ws_size,
                              hipStream_t stream) {
    const float* density = (const float*)d_in[0];
    const float* feature = (const float*)d_in[1];
    const float* depth   = (const float*)d_in[2];
    float* out = (float*)d_out;

    const long ND  = in_sizes[0];
    const long NDC = in_sizes[1];
    const int C = (int)(NDC / ND);
    const int N = out_size / (C + 1);
    const int D = (int)(ND / N);

    if (D == 128 && C == 3) {
        const int blocks = (N + 7) / 8;  // 8 rays per 256-thread block (2/wave)
        volrend_d128<<<blocks, 256, 0, stream>>>(density, feature, depth,
                                                 out, out + (size_t)N * 3, N);
    } else {
        const int threads = 256;
        volrend_generic<<<(N + threads - 1) / threads, threads, 0, stream>>>(
            density, feature, depth, out, N, D, C);
    }
}